// Round 1
// baseline (121.661 us; speedup 1.0000x reference)
//
#include <hip/hip_runtime.h>
#include <hip/hip_bf16.h>

#define NB 8
#define NC 128
#define NH 48
#define NW 64
#define NS 3072  // NH*NW
#define EPSF 1e-6f

typedef __bf16 bf16x8 __attribute__((ext_vector_type(8)));
typedef float f32x4 __attribute__((ext_vector_type(4)));

// ---------------------------------------------------------------------------
// Transpose + convert: src f32 [B][C][S] -> dst bf16 [B][S][C]
// REMAP=1: dst row k = (f&63)*NH + (f>>6)   (x: k = v*H + u, f = u*W + v)
// REMAP=0: dst row k = f                    (y: n = i*W + j)
// ---------------------------------------------------------------------------
template <int REMAP>
__global__ __launch_bounds__(256) void transpose_to_bf16(
    const float* __restrict__ src, __hip_bfloat16* __restrict__ dst) {
  __shared__ __hip_bfloat16 tile[32][33];
  const int b = blockIdx.z;
  const int c0 = blockIdx.y * 32;
  const int f0 = blockIdx.x * 32;
  const int t = threadIdx.x;

  const int fi = t & 31, ci0 = t >> 5;
  const float* sp = src + ((size_t)b * NC + c0) * NS + f0;
#pragma unroll
  for (int i = 0; i < 4; ++i) {
    int ci = ci0 + i * 8;
    tile[ci][fi] = __float2bfloat16(sp[(size_t)ci * NS + fi]);
  }
  __syncthreads();

  const int c = t & 31, fo0 = t >> 5;
#pragma unroll
  for (int i = 0; i < 4; ++i) {
    int fo = fo0 + i * 8;
    int f = f0 + fo;
    int k = REMAP ? ((f & 63) * NH + (f >> 6)) : f;
    dst[((size_t)b * NS + k) * NC + c0 + c] = tile[c][fo];
  }
}

// ---------------------------------------------------------------------------
// GEMM: T[m][n] = sum_c AT[b][mt*128+m][c] * BT[b][nt*128+n][c], K=C=128.
// WRITE=false: part[mt][b][nt*128+n] = sum_m relu(T)^2   (column partials)
// WRITE=true : out[b][mt*128+m][nt*128+n] = relu(T) * rn[b][nt*128+n]
// Tile 128x128, 4 waves (2x2 of 64x64), full K staged once (64 KB LDS).
// LDS rows are 128 bf16 = 256 B = 16 granules of 16 B; granule XOR-swizzled
// with (row&7) on both write and read.
// ---------------------------------------------------------------------------
template <bool WRITE>
__global__ __launch_bounds__(256, 2) void corr_gemm(
    const __hip_bfloat16* __restrict__ AT, const __hip_bfloat16* __restrict__ BT,
    const float* __restrict__ rn, float* __restrict__ part,
    float* __restrict__ out) {
  __shared__ uint4 smem4[4096];  // 64 KB: As = first 32 KB, Bs = second
  char* smem = (char*)smem4;
  const int nt = blockIdx.x, mt = blockIdx.y, b = blockIdx.z;
  const int t = threadIdx.x;
  const int lane = t & 63, wid = t >> 6;
  const int wm = wid >> 1, wn = wid & 1;
  const int l15 = lane & 15, kg = lane >> 4;

  // ---- stage both tiles (each a contiguous 32 KB block in global) ----
  const uint4* Ag = (const uint4*)(AT + ((size_t)b * NS + mt * 128) * NC);
  const uint4* Bg = (const uint4*)(BT + ((size_t)b * NS + nt * 128) * NC);
#pragma unroll
  for (int i = 0; i < 8; ++i) {
    int G = i * 256 + t;          // granule index 0..2047
    int row = G >> 4, g = G & 15; // 16 granules per row
    int gs = g ^ (row & 7);
    *(uint4*)(smem + row * 256 + gs * 16) = Ag[G];
    *(uint4*)(smem + 32768 + row * 256 + gs * 16) = Bg[G];
  }
  __syncthreads();

  // ---- MFMA main: 4 K-steps of 32, 16 MFMA each ----
  f32x4 acc[4][4] = {};
  const int rx = l15 & 7;
#pragma unroll
  for (int kk = 0; kk < 4; ++kk) {
    int g = (kk * 4 + kg) ^ rx;  // granule within row for this lane
    bf16x8 a[4], bb[4];
#pragma unroll
    for (int mi = 0; mi < 4; ++mi) {
      int row = wm * 64 + mi * 16 + l15;
      a[mi] = *(const bf16x8*)(smem + row * 256 + g * 16);
    }
#pragma unroll
    for (int ni = 0; ni < 4; ++ni) {
      int row = wn * 64 + ni * 16 + l15;
      bb[ni] = *(const bf16x8*)(smem + 32768 + row * 256 + g * 16);
    }
#pragma unroll
    for (int mi = 0; mi < 4; ++mi)
#pragma unroll
      for (int ni = 0; ni < 4; ++ni)
        acc[mi][ni] = __builtin_amdgcn_mfma_f32_16x16x32_bf16(
            a[mi], bb[ni], acc[mi][ni], 0, 0, 0);
  }

  if (!WRITE) {
    // per-column (n) sum of relu^2 over this tile's 128 rows
    float cs[4] = {0.f, 0.f, 0.f, 0.f};
#pragma unroll
    for (int ni = 0; ni < 4; ++ni)
#pragma unroll
      for (int mi = 0; mi < 4; ++mi)
#pragma unroll
        for (int r = 0; r < 4; ++r) {
          float v = fmaxf(acc[mi][ni][r], 0.f);
          cs[ni] += v * v;
        }
#pragma unroll
    for (int ni = 0; ni < 4; ++ni) {
      cs[ni] += __shfl_xor(cs[ni], 16, 64);
      cs[ni] += __shfl_xor(cs[ni], 32, 64);
    }
    __syncthreads();  // done reading As/Bs; reuse LDS for cross-wave reduce
    float* csum = (float*)smem;  // [2][128]
    if (kg == 0) {
#pragma unroll
      for (int ni = 0; ni < 4; ++ni)
        csum[wm * 128 + wn * 64 + ni * 16 + l15] = cs[ni];
    }
    __syncthreads();
    if (t < 128) {
      float s = csum[t] + csum[128 + t];
      part[(size_t)mt * (NB * NS) + (size_t)b * NS + nt * 128 + t] = s;
    }
  } else {
    const float* rnb = rn + (size_t)b * NS + nt * 128 + wn * 64;
    float rnv[4];
#pragma unroll
    for (int ni = 0; ni < 4; ++ni) rnv[ni] = rnb[ni * 16 + l15];
    float* ob = out + (size_t)b * NS * NS + (size_t)(mt * 128 + wm * 64) * NS +
                nt * 128 + wn * 64;
#pragma unroll
    for (int mi = 0; mi < 4; ++mi)
#pragma unroll
      for (int r = 0; r < 4; ++r) {
        size_t rowoff = (size_t)(mi * 16 + kg * 4 + r) * NS;
#pragma unroll
        for (int ni = 0; ni < 4; ++ni) {
          float v = fmaxf(acc[mi][ni][r], 0.f) * rnv[ni];
          __builtin_nontemporal_store(v, &ob[rowoff + ni * 16 + l15]);
        }
      }
  }
}

// ---------------------------------------------------------------------------
// rn[b*NS+n] = rsqrt( sum_mt part[mt][b][n] + eps )
// ---------------------------------------------------------------------------
__global__ __launch_bounds__(256) void reduce_norm(
    const float* __restrict__ part, float* __restrict__ rn) {
  int i = blockIdx.x * 256 + threadIdx.x;  // 0 .. NB*NS-1
  float s = 0.f;
#pragma unroll
  for (int mt = 0; mt < 24; ++mt) s += part[(size_t)mt * (NB * NS) + i];
  rn[i] = rsqrtf(s + EPSF);
}

extern "C" void kernel_launch(void* const* d_in, const int* in_sizes, int n_in,
                              void* d_out, int out_size, void* d_ws,
                              size_t ws_size, hipStream_t stream) {
  const float* x = (const float*)d_in[0];
  const float* y = (const float*)d_in[1];
  float* out = (float*)d_out;
  char* ws = (char*)d_ws;

  const size_t AT_OFF = 0;                     // 8*3072*128*2 = 6,291,456
  const size_t BT_OFF = 6291456;               // + 6,291,456
  const size_t PART_OFF = 12582912;            // 24*24576*4 = 2,359,296
  const size_t RN_OFF = 14942208;              // 24576*4 = 98,304
  const size_t NEED = 15040512;
  if (ws_size < NEED) return;  // insufficient scratch — would read garbage

  __hip_bfloat16* AT = (__hip_bfloat16*)(ws + AT_OFF);
  __hip_bfloat16* BT = (__hip_bfloat16*)(ws + BT_OFF);
  float* part = (float*)(ws + PART_OFF);
  float* rn = (float*)(ws + RN_OFF);

  dim3 tb(256);
  transpose_to_bf16<1><<<dim3(96, 4, 8), tb, 0, stream>>>(x, AT);
  transpose_to_bf16<0><<<dim3(96, 4, 8), tb, 0, stream>>>(y, BT);
  corr_gemm<false><<<dim3(24, 24, 8), tb, 0, stream>>>(AT, BT, nullptr,
                                                       part, nullptr);
  reduce_norm<<<dim3(96), tb, 0, stream>>>(part, rn);
  corr_gemm<true><<<dim3(24, 24, 8), tb, 0, stream>>>(AT, BT, rn, nullptr,
                                                      out);
}

// Round 2
// 114.513 us; speedup vs baseline: 1.0624x; 1.0624x over previous
//
#include <hip/hip_runtime.h>
#include <hip/hip_bf16.h>

#define NB 8
#define NC 128
#define NH 48
#define NW 64
#define NS 3072  // NH*NW
#define EPSF 1e-6f

#define GLOBAL_AS __attribute__((address_space(1)))
#define LDS_AS __attribute__((address_space(3)))

typedef __bf16 bf16x8 __attribute__((ext_vector_type(8)));
typedef float f32x4 __attribute__((ext_vector_type(4)));

// ---------------------------------------------------------------------------
// Fused transpose+convert for BOTH inputs: f32 [B][C][S] -> bf16 [B][S][C].
// blockIdx.z: z&7 = batch, z>>3 = which (0 = x with k-remap, 1 = y identity).
// Tile: 32 f-rows x 64 channels, f32 LDS [32][65] (conflict-free both phases).
// ---------------------------------------------------------------------------
__global__ __launch_bounds__(256) void transpose_both(
    const float* __restrict__ x, const float* __restrict__ y,
    __hip_bfloat16* __restrict__ AT, __hip_bfloat16* __restrict__ BT) {
  __shared__ float tile[32][65];
  const int z = blockIdx.z;
  const int which = z >> 3, b = z & 7;
  const float* src = which ? y : x;
  __hip_bfloat16* dst = which ? BT : AT;
  const int f0 = blockIdx.x * 32, c0 = blockIdx.y * 64;
  const int t = threadIdx.x;

  const int fi = t & 31, ci0 = t >> 5;
  const float* sp = src + ((size_t)b * NC + c0) * NS + f0;
#pragma unroll
  for (int i = 0; i < 8; ++i) {
    int ci = ci0 + i * 8;
    tile[fi][ci] = sp[(size_t)ci * NS + fi];
  }
  __syncthreads();

  const int co = t & 63, fo0 = t >> 6;
#pragma unroll
  for (int i = 0; i < 8; ++i) {
    int fo = fo0 + i * 4;
    int f = f0 + fo;
    int k = which ? f : ((f & 63) * NH + (f >> 6));  // x: k = v*H + u
    dst[((size_t)b * NS + k) * NC + c0 + co] = __float2bfloat16(tile[fo][co]);
  }
}

// ---------------------------------------------------------------------------
// GEMM: T[m][n] = sum_c AT[b][mt*128+m][c] * BT[b][nt*128+n][c], K=C=128.
// Grid is 1D (4608); b = id&7 pins batch to XCD (8 batches = 8 XCDs) so each
// XCD's 1.57 MB working set stays in its private L2.
// Staging: global_load_lds width=16, linear LDS dest, INVERSE-swizzled global
// source; LDS granule (row, gs) holds global granule (row, gs^(row&7)), so the
// read side's  g_lds = g ^ (row&7)  finds logical granule g (identical layout
// to the verified round-1 kernel).
// WRITE=false: part_out[mt][b][n] = sum_m relu(T)^2
// WRITE=true : out[b][m][n] = relu(T) * rsqrt(sum_mt part_in + eps)
//              (rn fused: computed per-block from partials into LDS)
// ---------------------------------------------------------------------------
template <bool WRITE>
__global__ __launch_bounds__(256, 2) void corr_gemm(
    const __hip_bfloat16* __restrict__ AT,
    const __hip_bfloat16* __restrict__ BT,
    const float* __restrict__ part_in, float* __restrict__ part_out,
    float* __restrict__ out) {
  __shared__ char smem[66560];  // 64 KB tiles (A then B) + 512 B rn cache
  float* rnc = (float*)(smem + 65536);
  const int id = blockIdx.x;
  const int b = id & 7;
  const int tl = id >> 3;
  const int mt = tl / 24, nt = tl - mt * 24;
  const int t = threadIdx.x;
  const int lane = t & 63, wid = t >> 6;
  const int wm = wid >> 1, wn = wid & 1;
  const int l15 = lane & 15, kg = lane >> 4;

  // ---- async stage both 32 KB tiles ----
  const char* Ag = (const char*)(AT + ((size_t)b * NS + mt * 128) * NC);
  const char* Bg = (const char*)(BT + ((size_t)b * NS + nt * 128) * NC);
  {
    const int lr = lane >> 4, lg = lane & 15;
#pragma unroll
    for (int i = 0; i < 8; ++i) {
      int c = wid * 8 + i;        // 1 KB chunk index 0..31
      int row = c * 4 + lr;       // LDS row this lane lands in
      int g = lg ^ (row & 7);     // inverse swizzle on the SOURCE granule
      int go = row * 256 + g * 16;
      __builtin_amdgcn_global_load_lds((const GLOBAL_AS unsigned*)(Ag + go),
                                       (LDS_AS unsigned*)(smem + c * 1024),
                                       16, 0, 0);
      __builtin_amdgcn_global_load_lds(
          (const GLOBAL_AS unsigned*)(Bg + go),
          (LDS_AS unsigned*)(smem + 32768 + c * 1024), 16, 0, 0);
    }
  }
  if (WRITE) {
    // fused norm: rn for this block's 128 columns (overlaps with staging)
    if (t < 128) {
      float s = 0.f;
#pragma unroll
      for (int q = 0; q < 24; ++q)
        s += part_in[(size_t)q * (NB * NS) + (size_t)b * NS + nt * 128 + t];
      rnc[t] = rsqrtf(s + EPSF);
    }
  }
  __syncthreads();  // drains vmcnt (global_load_lds) + lgkm (rnc)

  // ---- MFMA main: 4 K-steps of 32, 16 MFMA each ----
  f32x4 acc[4][4] = {};
  const int rx = l15 & 7;
#pragma unroll
  for (int kk = 0; kk < 4; ++kk) {
    int g = (kk * 4 + kg) ^ rx;  // swizzled granule within row
    bf16x8 a[4], bb[4];
#pragma unroll
    for (int mi = 0; mi < 4; ++mi) {
      int row = wm * 64 + mi * 16 + l15;
      a[mi] = *(const bf16x8*)(smem + row * 256 + g * 16);
    }
#pragma unroll
    for (int ni = 0; ni < 4; ++ni) {
      int row = wn * 64 + ni * 16 + l15;
      bb[ni] = *(const bf16x8*)(smem + 32768 + row * 256 + g * 16);
    }
#pragma unroll
    for (int mi = 0; mi < 4; ++mi)
#pragma unroll
      for (int ni = 0; ni < 4; ++ni)
        acc[mi][ni] = __builtin_amdgcn_mfma_f32_16x16x32_bf16(
            a[mi], bb[ni], acc[mi][ni], 0, 0, 0);
  }

  if (!WRITE) {
    // per-column (n) sum of relu^2 over this tile's 128 rows
    float cs[4] = {0.f, 0.f, 0.f, 0.f};
#pragma unroll
    for (int ni = 0; ni < 4; ++ni)
#pragma unroll
      for (int mi = 0; mi < 4; ++mi)
#pragma unroll
        for (int r = 0; r < 4; ++r) {
          float v = fmaxf(acc[mi][ni][r], 0.f);
          cs[ni] += v * v;
        }
#pragma unroll
    for (int ni = 0; ni < 4; ++ni) {
      cs[ni] += __shfl_xor(cs[ni], 16, 64);
      cs[ni] += __shfl_xor(cs[ni], 32, 64);
    }
    __syncthreads();  // all waves done reading tiles; reuse LDS
    float* csum = (float*)smem;  // [2][128]
    if (kg == 0) {
#pragma unroll
      for (int ni = 0; ni < 4; ++ni)
        csum[wm * 128 + wn * 64 + ni * 16 + l15] = cs[ni];
    }
    __syncthreads();
    if (t < 128) {
      float s = csum[t] + csum[128 + t];
      part_out[(size_t)mt * (NB * NS) + (size_t)b * NS + nt * 128 + t] = s;
    }
  } else {
    float rnv[4];
#pragma unroll
    for (int ni = 0; ni < 4; ++ni) rnv[ni] = rnc[wn * 64 + ni * 16 + l15];
    float* ob = out + (size_t)b * NS * NS + (size_t)(mt * 128 + wm * 64) * NS +
                nt * 128 + wn * 64;
#pragma unroll
    for (int mi = 0; mi < 4; ++mi)
#pragma unroll
      for (int r = 0; r < 4; ++r) {
        size_t rowoff = (size_t)(mi * 16 + kg * 4 + r) * NS;
#pragma unroll
        for (int ni = 0; ni < 4; ++ni) {
          float v = fmaxf(acc[mi][ni][r], 0.f) * rnv[ni];
          __builtin_nontemporal_store(v, &ob[rowoff + ni * 16 + l15]);
        }
      }
  }
}

extern "C" void kernel_launch(void* const* d_in, const int* in_sizes, int n_in,
                              void* d_out, int out_size, void* d_ws,
                              size_t ws_size, hipStream_t stream) {
  const float* x = (const float*)d_in[0];
  const float* y = (const float*)d_in[1];
  float* out = (float*)d_out;
  char* ws = (char*)d_ws;

  const size_t AT_OFF = 0;           // 8*3072*128*2 = 6,291,456
  const size_t BT_OFF = 6291456;     // + 6,291,456
  const size_t PART_OFF = 12582912;  // 24*24576*4 = 2,359,296
  const size_t NEED = 14942208;
  if (ws_size < NEED) return;

  __hip_bfloat16* AT = (__hip_bfloat16*)(ws + AT_OFF);
  __hip_bfloat16* BT = (__hip_bfloat16*)(ws + BT_OFF);
  float* part = (float*)(ws + PART_OFF);

  dim3 tb(256);
  transpose_both<<<dim3(96, 2, 16), tb, 0, stream>>>(x, y, AT, BT);
  corr_gemm<false><<<dim3(4608), tb, 0, stream>>>(AT, BT, nullptr, part,
                                                  nullptr);
  corr_gemm<true><<<dim3(4608), tb, 0, stream>>>(AT, BT, part, nullptr, out);
}

// Round 3
// 99.854 us; speedup vs baseline: 1.2184x; 1.1468x over previous
//
#include <hip/hip_runtime.h>
#include <hip/hip_bf16.h>

#define NB 8
#define NC 128
#define NH 48
#define NW 64
#define NS 3072  // NH*NW
#define EPSF 1e-6f

#define GLOBAL_AS __attribute__((address_space(1)))
#define LDS_AS __attribute__((address_space(3)))

typedef __bf16 bf16x8 __attribute__((ext_vector_type(8)));
typedef float f32x4 __attribute__((ext_vector_type(4)));

// ---------------------------------------------------------------------------
// Fused transpose+convert for BOTH inputs: f32 [B][C][S] -> bf16 [B][S][C].
// 1D grid, b = id&7 so batch is pinned to XCD (round-robin dispatch) and the
// bf16 tiles land in the same XCD L2 that the GEMM passes read them from.
// Tile: 32 f-rows x 64 channels, f32 LDS [32][65] (conflict-free both phases).
// ---------------------------------------------------------------------------
__global__ __launch_bounds__(256) void transpose_both(
    const float* __restrict__ x, const float* __restrict__ y,
    __hip_bfloat16* __restrict__ AT, __hip_bfloat16* __restrict__ BT) {
  __shared__ float tile[32][65];
  const int id = blockIdx.x;
  const int b = id & 7;
  const int which = (id >> 3) & 1;
  const int rr = id >> 4;  // 0..191
  const int f0 = (rr % 96) * 32, c0 = (rr / 96) * 64;
  const float* src = which ? y : x;
  __hip_bfloat16* dst = which ? BT : AT;
  const int t = threadIdx.x;

  const int fi = t & 31, ci0 = t >> 5;
  const float* sp = src + ((size_t)b * NC + c0) * NS + f0;
#pragma unroll
  for (int i = 0; i < 8; ++i) {
    int ci = ci0 + i * 8;
    tile[fi][ci] = sp[(size_t)ci * NS + fi];
  }
  __syncthreads();

  const int co = t & 63, fo0 = t >> 6;
#pragma unroll
  for (int i = 0; i < 8; ++i) {
    int fo = fo0 + i * 4;
    int f = f0 + fo;
    int k = which ? f : ((f & 63) * NH + (f >> 6));  // x: k = v*H + u
    dst[((size_t)b * NS + k) * NC + c0 + co] = __float2bfloat16(tile[fo][co]);
  }
}

// ---------------------------------------------------------------------------
// GEMM: T[m][n] = sum_c AT[b][mt*128+m][c] * BT[b][nt*128+n][c], K=C=128.
// 1D grid (4608); b = id&7 pins batch to XCD.
// Staging: global_load_lds width=16, linear LDS dest, inverse-swizzled global
// source; read side uses g ^ (row&7) (layout identical to verified round-1).
// WRITE=false: part_out[mt][b][n] = sum_m relu(T)^2
// WRITE=true : out[b][m][n] = relu(T) * rsqrt(sum_mt part_in + eps).
//   Epilogue repacks the 128x128 f32 tile through LDS ([128][129] pad) so
//   each store is dwordx4 (16 B/lane): one wave instr = 2 rows x 512 B = 4
//   FULL 128 B lines -> no partial-line HBM writes, nt-safe.
// ---------------------------------------------------------------------------
template <bool WRITE>
__global__ __launch_bounds__(256, 2) void corr_gemm(
    const __hip_bfloat16* __restrict__ AT,
    const __hip_bfloat16* __restrict__ BT,
    const float* __restrict__ part_in, float* __restrict__ part_out,
    float* __restrict__ out) {
  __shared__ char smem[66560];  // 64 KB tiles (A,B) + 512 B rn; epilogue
                                // reuses first 66048 B as f32 [128][129]
  float* rnc = (float*)(smem + 65536);
  const int id = blockIdx.x;
  const int b = id & 7;
  const int tl = id >> 3;
  const int mt = tl / 24, nt = tl - mt * 24;
  const int t = threadIdx.x;
  const int lane = t & 63, wid = t >> 6;
  const int wm = wid >> 1, wn = wid & 1;
  const int l15 = lane & 15, kg = lane >> 4;

  // ---- async stage both 32 KB tiles ----
  const char* Ag = (const char*)(AT + ((size_t)b * NS + mt * 128) * NC);
  const char* Bg = (const char*)(BT + ((size_t)b * NS + nt * 128) * NC);
  {
    const int lr = lane >> 4, lg = lane & 15;
#pragma unroll
    for (int i = 0; i < 8; ++i) {
      int c = wid * 8 + i;        // 1 KB chunk index 0..31
      int row = c * 4 + lr;       // LDS row this lane lands in
      int g = lg ^ (row & 7);     // inverse swizzle on the SOURCE granule
      int go = row * 256 + g * 16;
      __builtin_amdgcn_global_load_lds((const GLOBAL_AS unsigned*)(Ag + go),
                                       (LDS_AS unsigned*)(smem + c * 1024),
                                       16, 0, 0);
      __builtin_amdgcn_global_load_lds(
          (const GLOBAL_AS unsigned*)(Bg + go),
          (LDS_AS unsigned*)(smem + 32768 + c * 1024), 16, 0, 0);
    }
  }
  if (WRITE) {
    // fused norm: rn for this block's 128 columns (overlaps with staging)
    if (t < 128) {
      float s = 0.f;
#pragma unroll
      for (int q = 0; q < 24; ++q)
        s += part_in[(size_t)q * (NB * NS) + (size_t)b * NS + nt * 128 + t];
      rnc[t] = rsqrtf(s + EPSF);
    }
  }
  __syncthreads();  // drains vmcnt (global_load_lds) + lgkm (rnc)

  // ---- MFMA main: 4 K-steps of 32, 16 MFMA each ----
  f32x4 acc[4][4] = {};
  const int rx = l15 & 7;
#pragma unroll
  for (int kk = 0; kk < 4; ++kk) {
    int g = (kk * 4 + kg) ^ rx;  // swizzled granule within row
    bf16x8 a[4], bb[4];
#pragma unroll
    for (int mi = 0; mi < 4; ++mi) {
      int row = wm * 64 + mi * 16 + l15;
      a[mi] = *(const bf16x8*)(smem + row * 256 + g * 16);
    }
#pragma unroll
    for (int ni = 0; ni < 4; ++ni) {
      int row = wn * 64 + ni * 16 + l15;
      bb[ni] = *(const bf16x8*)(smem + 32768 + row * 256 + g * 16);
    }
#pragma unroll
    for (int mi = 0; mi < 4; ++mi)
#pragma unroll
      for (int ni = 0; ni < 4; ++ni)
        acc[mi][ni] = __builtin_amdgcn_mfma_f32_16x16x32_bf16(
            a[mi], bb[ni], acc[mi][ni], 0, 0, 0);
  }

  if (!WRITE) {
    // per-column (n) sum of relu^2 over this tile's 128 rows
    float cs[4] = {0.f, 0.f, 0.f, 0.f};
#pragma unroll
    for (int ni = 0; ni < 4; ++ni)
#pragma unroll
      for (int mi = 0; mi < 4; ++mi)
#pragma unroll
        for (int r = 0; r < 4; ++r) {
          float v = fmaxf(acc[mi][ni][r], 0.f);
          cs[ni] += v * v;
        }
#pragma unroll
    for (int ni = 0; ni < 4; ++ni) {
      cs[ni] += __shfl_xor(cs[ni], 16, 64);
      cs[ni] += __shfl_xor(cs[ni], 32, 64);
    }
    __syncthreads();  // all waves done reading tiles; reuse LDS
    float* csum = (float*)smem;  // [2][128]
    if (kg == 0) {
#pragma unroll
      for (int ni = 0; ni < 4; ++ni)
        csum[wm * 128 + wn * 64 + ni * 16 + l15] = cs[ni];
    }
    __syncthreads();
    if (t < 128) {
      float s = csum[t] + csum[128 + t];
      part_out[(size_t)mt * (NB * NS) + (size_t)b * NS + nt * 128 + t] = s;
    }
  } else {
    // grab rn before LDS is repurposed
    float rnv[4];
#pragma unroll
    for (int ni = 0; ni < 4; ++ni) rnv[ni] = rnc[wn * 64 + ni * 16 + l15];
    __syncthreads();  // tiles + rnc fully consumed

    // repack scaled tile into f32 [128][129] (pad: worst-case 2-way = free)
    float* tf = (float*)smem;
#pragma unroll
    for (int mi = 0; mi < 4; ++mi)
#pragma unroll
      for (int ni = 0; ni < 4; ++ni)
#pragma unroll
        for (int r = 0; r < 4; ++r) {
          int row = wm * 64 + mi * 16 + kg * 4 + r;
          int col = wn * 64 + ni * 16 + l15;
          tf[row * 129 + col] = fmaxf(acc[mi][ni][r], 0.f) * rnv[ni];
        }
    __syncthreads();

    // stream out: 2 full rows x 512 B per wave instruction (all-full lines)
    float* ob = out + (size_t)b * NS * NS + (size_t)(mt * 128) * NS + nt * 128;
    const int rsub = t >> 5, c4 = (t & 31) * 4;
#pragma unroll
    for (int it = 0; it < 16; ++it) {
      int row = it * 8 + rsub;
      f32x4 v = *(const f32x4*)&tf[row * 129 + c4];
      __builtin_nontemporal_store(v, (f32x4*)&ob[(size_t)row * NS + c4]);
    }
  }
}

extern "C" void kernel_launch(void* const* d_in, const int* in_sizes, int n_in,
                              void* d_out, int out_size, void* d_ws,
                              size_t ws_size, hipStream_t stream) {
  const float* x = (const float*)d_in[0];
  const float* y = (const float*)d_in[1];
  float* out = (float*)d_out;
  char* ws = (char*)d_ws;

  const size_t AT_OFF = 0;           // 8*3072*128*2 = 6,291,456
  const size_t BT_OFF = 6291456;     // + 6,291,456
  const size_t PART_OFF = 12582912;  // 24*24576*4 = 2,359,296
  const size_t NEED = 14942208;
  if (ws_size < NEED) return;

  __hip_bfloat16* AT = (__hip_bfloat16*)(ws + AT_OFF);
  __hip_bfloat16* BT = (__hip_bfloat16*)(ws + BT_OFF);
  float* part = (float*)(ws + PART_OFF);

  dim3 tb(256);
  transpose_both<<<dim3(3072), tb, 0, stream>>>(x, y, AT, BT);
  corr_gemm<false><<<dim3(4608), tb, 0, stream>>>(AT, BT, nullptr, part,
                                                  nullptr);
  corr_gemm<true><<<dim3(4608), tb, 0, stream>>>(AT, BT, part, nullptr, out);
}